// Round 12
// baseline (69.157 us; speedup 1.0000x reference)
//
#include <hip/hip_runtime.h>
#include <cmath>

typedef unsigned short u16;
typedef __attribute__((ext_vector_type(8))) short s8v;    // 8 bf16 (4 VGPRs)
typedef __attribute__((ext_vector_type(4))) float f4v;    // 16x16 acc / float4
typedef __attribute__((ext_vector_type(16))) float f16v;  // 32x32 acc

__device__ __forceinline__ u16 f2bf(float f) {
    union { float f; unsigned u; } v; v.f = f;
    unsigned r = v.u + 0x7FFFu + ((v.u >> 16) & 1u);   // RNE
    return (u16)(r >> 16);
}
// fast tanh: 1 - 2/(1+exp2(2x*log2e)); |err| ~1e-6
__device__ __forceinline__ float tanh_fast(float x) {
    float e = __builtin_amdgcn_exp2f(x * 2.88539008177792681f);
    return 1.f - 2.f * __builtin_amdgcn_rcpf(1.f + e);
}
// 16x16 subtile swizzled slot (gemm1 input staging; verified R5)
__device__ __forceinline__ int wslot(int row, int c) {
    return ((((c >> 2) << 6) | ((c & 3) << 4) | (row & 15)) ^ c);
}
// fragment-layout flat u16 index for element (n,k), 32x32 frags:
// lane = (n&31) + ((k>>3)&1)*32; j = k&7; tile (n>>5, k>>4)
__device__ __forceinline__ size_t fragoff(int n, int k) {
    return (((size_t)(n >> 5) * 64 + (k >> 4)) * 64 + (n & 31) + (((k >> 3) & 1) << 5)) * 8 + (k & 7);
}
// async global->LDS, 16B per lane; LDS dest = wave-uniform base + lane*16
__device__ __forceinline__ void gload_lds16(const u16* g, u16* l) {
    __builtin_amdgcn_global_load_lds(
        (const __attribute__((address_space(1))) void*)g,
        (__attribute__((address_space(3))) void*)l,
        16, 0, 0);
}

// ---------------------------------------------------------------------------
// prep (grid 32x32, 256 thr):  (R9 verbatim)
// ---------------------------------------------------------------------------
__launch_bounds__(256)
__global__ void cnf_prep(const float* __restrict__ x, const float* __restrict__ W1,
                         const float* __restrict__ W2, const float* __restrict__ W3,
                         u16* __restrict__ W2Tf, u16* __restrict__ VTf,
                         u16* __restrict__ xb, u16* __restrict__ W1T,
                         u16* __restrict__ W3Tf, float* __restrict__ trJ)
{
    __shared__ float w2s[32][33];
    __shared__ __align__(16) float w1s[64][36];   // [i][p], 16B-aligned rows
    const int a = blockIdx.x * 32;   // p / k (rows of W2)
    const int b = blockIdx.y * 32;   // q / n (cols of W2)
    const int t = threadIdx.x;

    #pragma unroll
    for (int it = 0; it < 4; ++it) {
        int idx = t + it * 256;
        w2s[idx >> 5][idx & 31] = W2[(a + (idx >> 5)) * 1024 + b + (idx & 31)];
    }
    #pragma unroll
    for (int it = 0; it < 8; ++it) {
        int idx = t + it * 256;
        w1s[idx >> 5][idx & 31] = W1[(idx >> 5) * 1024 + a + (idx & 31)];
    }
    __syncthreads();

    #pragma unroll
    for (int it = 0; it < 4; ++it) {
        int idx = t + it * 256;
        int rr = idx >> 5, cc = idx & 31;
        W2Tf[fragoff(b + rr, a + cc)] = f2bf(w2s[cc][rr]);
    }
    {
        const int q = t >> 3, pg = t & 7;
        const float* w3row = W3 + (b + q) * 64;
        f4v u = f4v{0.f, 0.f, 0.f, 0.f};
        #pragma unroll
        for (int i4 = 0; i4 < 16; ++i4) {
            f4v w3v = *(const f4v*)&w3row[i4 * 4];
            #pragma unroll
            for (int s = 0; s < 4; ++s) {
                f4v wv = *(const f4v*)&w1s[i4 * 4 + s][pg * 4];
                u += w3v[s] * wv;
            }
        }
        #pragma unroll
        for (int j = 0; j < 4; ++j) {
            const int pp = pg * 4 + j;
            VTf[fragoff(b + q, a + pp)] = f2bf(w2s[pp][q] * u[j]);
        }
    }
    {
        int bid = blockIdx.y * 32 + blockIdx.x;
        int e = bid * 256 + t;
        xb[e] = f2bf(x[(e >> 6) * 65 + 1 + (e & 63)]);
    }
    if (blockIdx.y == 0) {
        int pp = t >> 3, i0 = (t & 7) * 8;
        s8v v;
        #pragma unroll
        for (int j = 0; j < 8; ++j) v[j] = (short)f2bf(w1s[i0 + j][pp]);
        *(s8v*)&W1T[(a + pp) * 64 + i0] = v;
        if (t < 128) trJ[blockIdx.x * 128 + t] = 0.f;
    }
    if (blockIdx.y == 1) {
        int idx = blockIdx.x * 256 + t;
        int n = idx & 63, k0 = (idx >> 6) * 8;
        s8v v;
        #pragma unroll
        for (int j = 0; j < 8; ++j) v[j] = (short)f2bf(W3[(k0 + j) * 64 + n]);
        *(s8v*)&W3Tf[fragoff(n, k0)] = v;
    }
}

// ---------------------------------------------------------------------------
// gemm1 (MFMA 16x16x32): h1 = tanh(xb @ W1T^T + b1), g1 = 1-h1^2
// OUTPUT IN 32x32 A-FRAGMENT LAYOUT (h1f/g1f) via swizzled LDS transpose +
// frag-ordered contiguous 1KB stores (R7-verified epilogue).
// Block 128 rows x 64 cols, grid (32,16), 4 waves 2x2.
// ---------------------------------------------------------------------------
__launch_bounds__(256)
__global__ void cnf_gemm1(const u16* __restrict__ xb, const u16* __restrict__ W1T,
                          const float* __restrict__ b1,
                          u16* __restrict__ h1f, u16* __restrict__ g1f)
{
    __shared__ __align__(16) u16 lds[12 * 1024];   // 24 KB input staging
    __shared__ __align__(16) u16 hls[128 * 64];    // 16 KB
    __shared__ __align__(16) u16 gls[128 * 64];    // 16 KB
    const int t = threadIdx.x;
    const int wave = t >> 6, lane = t & 63;
    const int wm = wave >> 1, wn = wave & 1;
    const int g = lane >> 4, lr = lane & 15;
    const int arow0 = blockIdx.x * 128, bcol0 = blockIdx.y * 64;

    #pragma unroll
    for (int i = 0; i < 4; ++i) {
        int ch = t + i * 256, row = ch >> 3, c = ch & 7;
        *(s8v*)&lds[(row >> 4) * 1024 + wslot(row, c) * 8] =
            *(const s8v*)&xb[(arow0 + row) * 64 + c * 8];
    }
    #pragma unroll
    for (int i = 0; i < 2; ++i) {
        int ch = t + i * 256, row = ch >> 3, c = ch & 7;
        *(s8v*)&lds[(8 + (row >> 4)) * 1024 + wslot(row, c) * 8] =
            *(const s8v*)&W1T[(bcol0 + row) * 64 + c * 8];
    }
    __syncthreads();

    f4v acc[4][2];
    #pragma unroll
    for (int mi = 0; mi < 4; ++mi)
        #pragma unroll
        for (int ni = 0; ni < 2; ++ni) acc[mi][ni] = f4v{0.f,0.f,0.f,0.f};

    #pragma unroll
    for (int ks = 0; ks < 2; ++ks) {
        const int lo = (ks * 64 + (lane ^ ((ks * 4 + g) & 7))) * 8;
        s8v af[4], bf[2];
        #pragma unroll
        for (int mi = 0; mi < 4; ++mi) af[mi] = *(const s8v*)&lds[(wm * 4 + mi) * 1024 + lo];
        #pragma unroll
        for (int ni = 0; ni < 2; ++ni) bf[ni] = *(const s8v*)&lds[(8 + wn * 2 + ni) * 1024 + lo];
        #pragma unroll
        for (int mi = 0; mi < 4; ++mi)
            #pragma unroll
            for (int ni = 0; ni < 2; ++ni)
                acc[mi][ni] = __builtin_amdgcn_mfma_f32_16x16x32_bf16(af[mi], bf[ni], acc[mi][ni], 0, 0, 0);
    }

    // epilogue: h/g -> swizzled LDS tiles [row][col] (8-col chunk XOR row&7)
    #pragma unroll
    for (int mi = 0; mi < 4; ++mi) {
        const int rowl = wm * 64 + mi * 16 + g * 4;
        #pragma unroll
        for (int ni = 0; ni < 2; ++ni) {
            const int coll = wn * 32 + ni * 16 + lr;
            const float bv = b1[bcol0 + coll];
            const int cc = coll >> 3, jj = coll & 7;
            #pragma unroll
            for (int r = 0; r < 4; ++r) {
                const int row = rowl + r;
                float h = tanh_fast(acc[mi][ni][r] + bv);
                int idx = row * 64 + ((cc ^ (row & 7)) << 3) + jj;
                hls[idx] = f2bf(h);
                gls[idx] = f2bf(1.f - h * h);
            }
        }
    }
    __syncthreads();

    // frag-ordered read + coalesced 1KB-frag global stores
    const int rt0 = arow0 >> 5, kk0 = bcol0 >> 4;
    #pragma unroll
    for (int i = 0; i < 4; ++i) {
        const int tile = (i * 256 + t) >> 6;       // 0..15
        const int ln = t & 63;
        const int rt = tile >> 2, kk = tile & 3;
        const int row = rt * 32 + (ln & 31);
        const int kb = kk * 16 + (ln >> 5) * 8;
        const int src = row * 64 + (((kb >> 3) ^ (row & 7)) << 3);
        const size_t dst = ((size_t)(rt0 + rt) * 64 + (kk0 + kk)) * 512 + ln * 8;
        *(s8v*)&h1f[dst] = *(const s8v*)&hls[src];
        *(s8v*)&g1f[dst] = *(const s8v*)&gls[src];
    }
}

// ---------------------------------------------------------------------------
// mid: fused dual GEMM, K=1024, tile 128x128, 8 waves (512 thr),
// wave tile 64x32 (wrt=wave&1 row-half, wn=wave>>1 col-quarter).
// A (h1f/g1f, frag layout) staged via global_load_lds width=16 into
// frag-linear LDS (NO swizzle: linear dest + linear source + linear read).
// 2 LDS buffers ping-pong, ONE barrier per kt (m97 structure): stage kt+1 +
// B-prefetch issued before computing kt; barrier's vmcnt(0) drain covers both.
// B (W2Tf,VTf) direct per-wave reg loads (L2-resident, 4MB).
//   C2 = h1@W2 -> h2f (frag layout); T = g1@V -> trJ += rowsum(T*g2)
// Each wave stages frag (rt=wave>>1, kkh=wave&1): 1KB per matrix per kt.
// ---------------------------------------------------------------------------
#define STAGEA(kt, bb)                                                         \
    do { const int _kkg = (kt) * 2 + kwh;                                      \
         gload_lds16(h1f + ((size_t)rtg * 64 + _kkg) * 512 + lane * 8,         \
                     &lds[bb][wave * 512]);                                    \
         gload_lds16(g1f + ((size_t)rtg * 64 + _kkg) * 512 + lane * 8,         \
                     &lds[bb][4096 + wave * 512]);                             \
    } while (0)

#define LOADB(B, kkg)                                                          \
    do { _Pragma("unroll")                                                     \
         for (int _ks = 0; _ks < 2; ++_ks) {                                   \
             size_t _o = (((size_t)(ntb + wn) * 64 + (kkg) * 2 + _ks) * 64 + lane) * 8; \
             B[_ks*2 + 0] = *(const s8v*)&W2Tf[_o];                            \
             B[_ks*2 + 1] = *(const s8v*)&VTf[_o];                             \
         } } while (0)

#define MIDBODY(kt, Bc, Bn)                                                    \
    {                                                                          \
        if ((kt) < 31) { STAGEA((kt) + 1, ((kt) + 1) & 1); LOADB(Bn, (kt) + 1); } \
        const u16* buf = &lds[(kt) & 1][0];                                    \
        _Pragma("unroll")                                                      \
        for (int ks = 0; ks < 2; ++ks) {                                       \
            s8v a1[2], a2[2];                                                  \
            _Pragma("unroll")                                                  \
            for (int mt = 0; mt < 2; ++mt) {                                   \
                const int f = ((wrt * 2 + mt) * 2 + ks) * 512 + lane * 8;      \
                a1[mt] = *(const s8v*)&buf[f];                                 \
                a2[mt] = *(const s8v*)&buf[4096 + f];                          \
            }                                                                  \
            _Pragma("unroll")                                                  \
            for (int mt = 0; mt < 2; ++mt) {                                   \
                acc1[mt] = __builtin_amdgcn_mfma_f32_32x32x16_bf16(a1[mt], Bc[ks*2+0], acc1[mt], 0, 0, 0); \
                acc2[mt] = __builtin_amdgcn_mfma_f32_32x32x16_bf16(a2[mt], Bc[ks*2+1], acc2[mt], 0, 0, 0); \
            }                                                                  \
        }                                                                      \
        __syncthreads();                                                       \
    }

__launch_bounds__(512, 1)
__global__ void cnf_mid(const u16* __restrict__ h1f, const u16* __restrict__ g1f,
                        const u16* __restrict__ W2Tf, const u16* __restrict__ VTf,
                        const float* __restrict__ b2,
                        u16* __restrict__ h2f, float* __restrict__ trJ)
{
    __shared__ __align__(16) u16 lds[2][8192];   // 2 x 16 KiB (A frags)

    const int t = threadIdx.x;
    const int wave = t >> 6, lane = t & 63;
    const int wrt = wave & 1;          // row half (64 rows = 2 mtiles)
    const int wn  = wave >> 1;         // col quarter (32 cols = 1 ntile)
    const int bid = blockIdx.x;
    const int bx  = bid >> 3;          // row tile 0..31
    const int by  = bid & 7;           // col group 0..7
    const int arow0 = bx * 128;
    const int ntb = by * 4;
    const int rtg = bx * 4 + (wave >> 1);  // staged A frag row-tile (per wave)
    const int kwh = wave & 1;              // staged A frag k-half (per wave)

    f16v acc1[2], acc2[2];
    #pragma unroll
    for (int mt = 0; mt < 2; ++mt)
        #pragma unroll
        for (int r = 0; r < 16; ++r) { acc1[mt][r] = 0.f; acc2[mt][r] = 0.f; }

    s8v bA[4], bB[4];

    STAGEA(0, 0);
    LOADB(bA, 0);
    __syncthreads();

    for (int kt2 = 0; kt2 < 16; ++kt2) {
        const int kt = kt2 * 2;
        MIDBODY(kt,     bA, bB);
        MIDBODY(kt + 1, bB, bA);
    }

    // epilogue: h2 (frag layout) + trace reduction
    const int l31 = lane & 31, lh = lane >> 5;
    #pragma unroll
    for (int mt = 0; mt < 2; ++mt) {
        const int rt = (arow0 >> 5) + wrt * 2 + mt;
        const int q0 = (ntb + wn) * 32;
        const float bv = b2[q0 + l31];
        const size_t hb = (((size_t)rt * 64 + ((q0 + l31) >> 4)) * 64
                           + (((l31 >> 3) & 1) << 5)) * 8 + (l31 & 7) + lh * 32;
        float tr[16];
        #pragma unroll
        for (int r = 0; r < 16; ++r) {
            float hh = tanh_fast(acc1[mt][r] + bv);
            float gg = 1.f - hh * hh;
            h2f[hb + ((r & 3) + ((r >> 2) << 3)) * 8] = f2bf(hh);
            tr[r] = acc2[mt][r] * gg;
        }
        #pragma unroll
        for (int off = 1; off < 32; off <<= 1)
            #pragma unroll
            for (int r = 0; r < 16; ++r) tr[r] += __shfl_xor(tr[r], off);
        if (l31 == 0) {
            const int rowb = arow0 + (wrt * 2 + mt) * 32 + lh * 4;
            #pragma unroll
            for (int r = 0; r < 16; ++r)
                atomicAdd(&trJ[rowb + (r & 3) + ((r >> 2) << 3)], tr[r]);
        }
    }
}

// ---------------------------------------------------------------------------
// out: y = h2 @ W3 + b3, grid (128, 2): 32-row tiles x 2 col-halves.
// Wave-split K, LDS reduce, plain stores. nb==0 also writes out[:,0] = -trJ.
// ---------------------------------------------------------------------------
__launch_bounds__(256)
__global__ void cnf_out(const u16* __restrict__ h2f, const u16* __restrict__ W3Tf,
                        const float* __restrict__ b3, const float* __restrict__ trJ,
                        float* __restrict__ out)
{
    __shared__ float red[4][32][32];
    const int t = threadIdx.x;
    const int wave = t >> 6, lane = t & 63;
    const int rt = blockIdx.x;
    const int nb = blockIdx.y;          // column half (32 cols)

    f16v acc;
    #pragma unroll
    for (int r = 0; r < 16; ++r) acc[r] = 0.f;

    #pragma unroll
    for (int kki = 0; kki < 16; ++kki) {
        const int kk = wave * 16 + kki;
        s8v af = *(const s8v*)&h2f[(((size_t)rt * 64 + kk) * 64 + lane) * 8];
        s8v bf = *(const s8v*)&W3Tf[(((size_t)nb * 64 + kk) * 64 + lane) * 8];
        acc = __builtin_amdgcn_mfma_f32_32x32x16_bf16(af, bf, acc, 0, 0, 0);
    }
    const int l31 = lane & 31, lh = lane >> 5;
    #pragma unroll
    for (int r = 0; r < 16; ++r)
        red[wave][(r & 3) + ((r >> 2) << 3) + lh * 4][l31] = acc[r];
    __syncthreads();

    #pragma unroll
    for (int i = 0; i < 4; ++i) {
        int o = t + i * 256;
        int row = o >> 5, col = o & 31;
        float s = red[0][row][col] + red[1][row][col] + red[2][row][col]
                + red[3][row][col] + b3[nb * 32 + col];
        out[(size_t)(rt * 32 + row) * 65 + 1 + nb * 32 + col] = s;
    }
    if (nb == 0 && t < 32) out[(size_t)(rt * 32 + t) * 65] = -trJ[rt * 32 + t];
}

// ---------------------------------------------------------------------------
extern "C" void kernel_launch(void* const* d_in, const int* in_sizes, int n_in,
                              void* d_out, int out_size, void* d_ws, size_t ws_size,
                              hipStream_t stream) {
    const float* x  = (const float*)d_in[0];
    const float* W1 = (const float*)d_in[1];
    const float* b1 = (const float*)d_in[2];
    const float* W2 = (const float*)d_in[3];
    const float* b2 = (const float*)d_in[4];
    const float* W3 = (const float*)d_in[5];
    const float* b3 = (const float*)d_in[6];
    float* out = (float*)d_out;

    char* ws = (char*)d_ws;
    u16*   h1f = (u16*)(ws);                                  //  8 MB (frag layout)
    u16*   g1f = (u16*)(ws + (size_t)( 8u << 20));            //  8 MB (frag layout)
    u16*   h2f = (u16*)(ws + (size_t)(16u << 20));            //  8 MB (frag layout)
    u16*   W2T = (u16*)(ws + (size_t)(24u << 20));            //  2 MB (frag layout)
    u16*   VTb = (u16*)(ws + (size_t)(26u << 20));            //  2 MB (frag layout)
    float* trJ = (float*)(ws + (size_t)(28u << 20));          // 16 KB
    u16*   xbb = (u16*)(ws + (size_t)(28u << 20) + 65536);    // 512 KB
    u16*   W1T = (u16*)(ws + (size_t)(28u << 20) + 65536 + 524288);             // 128 KB
    u16*   W3T = (u16*)(ws + (size_t)(28u << 20) + 65536 + 524288 + 131072);    // 128 KB (frag)

    cnf_prep <<<dim3(32, 32), 256, 0, stream>>>(x, W1, W2, W3, W2T, VTb, xbb, W1T, W3T, trJ);
    cnf_gemm1<<<dim3(32, 16), 256, 0, stream>>>(xbb, W1T, b1, h1f, g1f);
    cnf_mid  <<<256,          512, 0, stream>>>(h1f, g1f, W2T, VTb, b2, h2f, trJ);
    cnf_out  <<<dim3(128, 2), 256, 0, stream>>>(h2f, W3T, b3, trJ, out);
}

// Round 13
// 58.034 us; speedup vs baseline: 1.1917x; 1.1917x over previous
//
#include <hip/hip_runtime.h>
#include <cmath>

typedef unsigned short u16;
typedef __attribute__((ext_vector_type(8))) short s8v;    // 8 bf16 (4 VGPRs)
typedef __attribute__((ext_vector_type(4))) float f4v;    // 16x16 acc / float4
typedef __attribute__((ext_vector_type(16))) float f16v;  // 32x32 acc

__device__ __forceinline__ u16 f2bf(float f) {
    union { float f; unsigned u; } v; v.f = f;
    unsigned r = v.u + 0x7FFFu + ((v.u >> 16) & 1u);   // RNE
    return (u16)(r >> 16);
}
// fast tanh: 1 - 2/(1+exp2(2x*log2e)); |err| ~1e-6
__device__ __forceinline__ float tanh_fast(float x) {
    float e = __builtin_amdgcn_exp2f(x * 2.88539008177792681f);
    return 1.f - 2.f * __builtin_amdgcn_rcpf(1.f + e);
}
// 16x16 subtile swizzled slot (gemm1 input staging; verified R5)
__device__ __forceinline__ int wslot(int row, int c) {
    return ((((c >> 2) << 6) | ((c & 3) << 4) | (row & 15)) ^ c);
}
// fragment-layout flat u16 index for element (n,k), 32x32 frags:
// lane = (n&31) + ((k>>3)&1)*32; j = k&7; tile (n>>5, k>>4)
__device__ __forceinline__ size_t fragoff(int n, int k) {
    return (((size_t)(n >> 5) * 64 + (k >> 4)) * 64 + (n & 31) + (((k >> 3) & 1) << 5)) * 8 + (k & 7);
}

// ---------------------------------------------------------------------------
// prep (grid 32x32, 256 thr):  (R9 verbatim)
// ---------------------------------------------------------------------------
__launch_bounds__(256)
__global__ void cnf_prep(const float* __restrict__ x, const float* __restrict__ W1,
                         const float* __restrict__ W2, const float* __restrict__ W3,
                         u16* __restrict__ W2Tf, u16* __restrict__ VTf,
                         u16* __restrict__ xb, u16* __restrict__ W1T,
                         u16* __restrict__ W3Tf, float* __restrict__ trJ)
{
    __shared__ float w2s[32][33];
    __shared__ __align__(16) float w1s[64][36];   // [i][p], 16B-aligned rows
    const int a = blockIdx.x * 32;   // p / k (rows of W2)
    const int b = blockIdx.y * 32;   // q / n (cols of W2)
    const int t = threadIdx.x;

    #pragma unroll
    for (int it = 0; it < 4; ++it) {
        int idx = t + it * 256;
        w2s[idx >> 5][idx & 31] = W2[(a + (idx >> 5)) * 1024 + b + (idx & 31)];
    }
    #pragma unroll
    for (int it = 0; it < 8; ++it) {
        int idx = t + it * 256;
        w1s[idx >> 5][idx & 31] = W1[(idx >> 5) * 1024 + a + (idx & 31)];
    }
    __syncthreads();

    #pragma unroll
    for (int it = 0; it < 4; ++it) {
        int idx = t + it * 256;
        int rr = idx >> 5, cc = idx & 31;
        W2Tf[fragoff(b + rr, a + cc)] = f2bf(w2s[cc][rr]);
    }
    {
        const int q = t >> 3, pg = t & 7;
        const float* w3row = W3 + (b + q) * 64;
        f4v u = f4v{0.f, 0.f, 0.f, 0.f};
        #pragma unroll
        for (int i4 = 0; i4 < 16; ++i4) {
            f4v w3v = *(const f4v*)&w3row[i4 * 4];
            #pragma unroll
            for (int s = 0; s < 4; ++s) {
                f4v wv = *(const f4v*)&w1s[i4 * 4 + s][pg * 4];
                u += w3v[s] * wv;
            }
        }
        #pragma unroll
        for (int j = 0; j < 4; ++j) {
            const int pp = pg * 4 + j;
            VTf[fragoff(b + q, a + pp)] = f2bf(w2s[pp][q] * u[j]);
        }
    }
    {
        int bid = blockIdx.y * 32 + blockIdx.x;
        int e = bid * 256 + t;
        xb[e] = f2bf(x[(e >> 6) * 65 + 1 + (e & 63)]);
    }
    if (blockIdx.y == 0) {
        int pp = t >> 3, i0 = (t & 7) * 8;
        s8v v;
        #pragma unroll
        for (int j = 0; j < 8; ++j) v[j] = (short)f2bf(w1s[i0 + j][pp]);
        *(s8v*)&W1T[(a + pp) * 64 + i0] = v;
        if (t < 128) trJ[blockIdx.x * 128 + t] = 0.f;
    }
    if (blockIdx.y == 1) {
        int idx = blockIdx.x * 256 + t;
        int n = idx & 63, k0 = (idx >> 6) * 8;
        s8v v;
        #pragma unroll
        for (int j = 0; j < 8; ++j) v[j] = (short)f2bf(W3[(k0 + j) * 64 + n]);
        *(s8v*)&W3Tf[fragoff(n, k0)] = v;
    }
}

// ---------------------------------------------------------------------------
// gemm1 (MFMA 16x16x32): h1 = tanh(xb @ W1T^T + b1), g1 = 1-h1^2
// OUTPUT IN 32x32 A-FRAGMENT LAYOUT (h1f/g1f).  (R12 verbatim, verified)
// ---------------------------------------------------------------------------
__launch_bounds__(256)
__global__ void cnf_gemm1(const u16* __restrict__ xb, const u16* __restrict__ W1T,
                          const float* __restrict__ b1,
                          u16* __restrict__ h1f, u16* __restrict__ g1f)
{
    __shared__ __align__(16) u16 lds[12 * 1024];   // 24 KB input staging
    __shared__ __align__(16) u16 hls[128 * 64];    // 16 KB
    __shared__ __align__(16) u16 gls[128 * 64];    // 16 KB
    const int t = threadIdx.x;
    const int wave = t >> 6, lane = t & 63;
    const int wm = wave >> 1, wn = wave & 1;
    const int g = lane >> 4, lr = lane & 15;
    const int arow0 = blockIdx.x * 128, bcol0 = blockIdx.y * 64;

    #pragma unroll
    for (int i = 0; i < 4; ++i) {
        int ch = t + i * 256, row = ch >> 3, c = ch & 7;
        *(s8v*)&lds[(row >> 4) * 1024 + wslot(row, c) * 8] =
            *(const s8v*)&xb[(arow0 + row) * 64 + c * 8];
    }
    #pragma unroll
    for (int i = 0; i < 2; ++i) {
        int ch = t + i * 256, row = ch >> 3, c = ch & 7;
        *(s8v*)&lds[(8 + (row >> 4)) * 1024 + wslot(row, c) * 8] =
            *(const s8v*)&W1T[(bcol0 + row) * 64 + c * 8];
    }
    __syncthreads();

    f4v acc[4][2];
    #pragma unroll
    for (int mi = 0; mi < 4; ++mi)
        #pragma unroll
        for (int ni = 0; ni < 2; ++ni) acc[mi][ni] = f4v{0.f,0.f,0.f,0.f};

    #pragma unroll
    for (int ks = 0; ks < 2; ++ks) {
        const int lo = (ks * 64 + (lane ^ ((ks * 4 + g) & 7))) * 8;
        s8v af[4], bf[2];
        #pragma unroll
        for (int mi = 0; mi < 4; ++mi) af[mi] = *(const s8v*)&lds[(wm * 4 + mi) * 1024 + lo];
        #pragma unroll
        for (int ni = 0; ni < 2; ++ni) bf[ni] = *(const s8v*)&lds[(8 + wn * 2 + ni) * 1024 + lo];
        #pragma unroll
        for (int mi = 0; mi < 4; ++mi)
            #pragma unroll
            for (int ni = 0; ni < 2; ++ni)
                acc[mi][ni] = __builtin_amdgcn_mfma_f32_16x16x32_bf16(af[mi], bf[ni], acc[mi][ni], 0, 0, 0);
    }

    #pragma unroll
    for (int mi = 0; mi < 4; ++mi) {
        const int rowl = wm * 64 + mi * 16 + g * 4;
        #pragma unroll
        for (int ni = 0; ni < 2; ++ni) {
            const int coll = wn * 32 + ni * 16 + lr;
            const float bv = b1[bcol0 + coll];
            const int cc = coll >> 3, jj = coll & 7;
            #pragma unroll
            for (int r = 0; r < 4; ++r) {
                const int row = rowl + r;
                float h = tanh_fast(acc[mi][ni][r] + bv);
                int idx = row * 64 + ((cc ^ (row & 7)) << 3) + jj;
                hls[idx] = f2bf(h);
                gls[idx] = f2bf(1.f - h * h);
            }
        }
    }
    __syncthreads();

    const int rt0 = arow0 >> 5, kk0 = bcol0 >> 4;
    #pragma unroll
    for (int i = 0; i < 4; ++i) {
        const int tile = (i * 256 + t) >> 6;       // 0..15
        const int ln = t & 63;
        const int rt = tile >> 2, kk = tile & 3;
        const int row = rt * 32 + (ln & 31);
        const int kb = kk * 16 + (ln >> 5) * 8;
        const int src = row * 64 + (((kb >> 3) ^ (row & 7)) << 3);
        const size_t dst = ((size_t)(rt0 + rt) * 64 + (kk0 + kk)) * 512 + ln * 8;
        *(s8v*)&h1f[dst] = *(const s8v*)&hls[src];
        *(s8v*)&g1f[dst] = *(const s8v*)&gls[src];
    }
}

// ---------------------------------------------------------------------------
// mid: fused dual GEMM, K=1024, tile 128x128, 8 waves (512 thr),
// wave tile 64x32 (wrt=wave&1, wn=wave>>1). BK=64 PHASES (16 barriers).
// A (h1f/g1f frag layout) reg-staged 2 PHASES ahead -> linear LDS ping-pong
// (32KB/buf). Raw s_barrier + lgkmcnt(0) ONLY - vmcnt NOT drained at barrier,
// so A/B global prefetch stays in flight across phases (T4-lite).
// B (W2Tf,VTf) per-wave reg frag loads, 1 phase ahead.
//   C2 = h1@W2 -> h2f (frag layout); T = g1@V -> trJ += rowsum(T*g2)
// ---------------------------------------------------------------------------
#define LOADB(B, pp)                                                           \
    do { _Pragma("unroll")                                                     \
         for (int _ks = 0; _ks < 4; ++_ks) {                                   \
             size_t _o = (((size_t)(ntb + wn) * 64 + (pp) * 4 + _ks) * 64 + lane) * 8; \
             B[_ks*2 + 0] = *(const s8v*)&W2Tf[_o];                            \
             B[_ks*2 + 1] = *(const s8v*)&VTf[_o];                             \
         } } while (0)

#define PHASE(p, AwH, AwG, AlH, AlG, Bc, Bn)                                   \
    {                                                                          \
        if ((p) < 14) {                                                        \
            const size_t _go = (size_t)((p) + 2) * 2048;                       \
            AlH[0] = *(const s8v*)(h1f + sgo0 + _go);                          \
            AlH[1] = *(const s8v*)(h1f + sgo1 + _go);                          \
            AlG[0] = *(const s8v*)(g1f + sgo0 + _go);                          \
            AlG[1] = *(const s8v*)(g1f + sgo1 + _go);                          \
        }                                                                      \
        if ((p) < 15) {                                                        \
            u16* _wb = &lds[((p) + 1) & 1][0];                                 \
            *(s8v*)&_wb[sdo0] = AwH[0];        *(s8v*)&_wb[sdo1] = AwH[1];     \
            *(s8v*)&_wb[8192 + sdo0] = AwG[0]; *(s8v*)&_wb[8192 + sdo1] = AwG[1]; \
            LOADB(Bn, (p) + 1);                                                \
        }                                                                      \
        const u16* _buf = &lds[(p) & 1][0];                                    \
        _Pragma("unroll")                                                      \
        for (int ks = 0; ks < 4; ++ks) {                                       \
            s8v a1[2], a2[2];                                                  \
            _Pragma("unroll")                                                  \
            for (int mt = 0; mt < 2; ++mt) {                                   \
                const int f = ((wrt * 2 + mt) * 4 + ks) * 512 + lane * 8;      \
                a1[mt] = *(const s8v*)&_buf[f];                                \
                a2[mt] = *(const s8v*)&_buf[8192 + f];                         \
            }                                                                  \
            _Pragma("unroll")                                                  \
            for (int mt = 0; mt < 2; ++mt) {                                   \
                acc1[mt] = __builtin_amdgcn_mfma_f32_32x32x16_bf16(a1[mt], Bc[ks*2+0], acc1[mt], 0, 0, 0); \
                acc2[mt] = __builtin_amdgcn_mfma_f32_32x32x16_bf16(a2[mt], Bc[ks*2+1], acc2[mt], 0, 0, 0); \
            }                                                                  \
        }                                                                      \
        if ((p) < 15) {                                                        \
            asm volatile("s_waitcnt lgkmcnt(0)" ::: "memory");                 \
            __builtin_amdgcn_s_barrier();                                      \
        }                                                                      \
    }

__launch_bounds__(512, 1)
__global__ void cnf_mid(const u16* __restrict__ h1f, const u16* __restrict__ g1f,
                        const u16* __restrict__ W2Tf, const u16* __restrict__ VTf,
                        const float* __restrict__ b2,
                        u16* __restrict__ h2f, float* __restrict__ trJ)
{
    __shared__ __align__(16) u16 lds[2][16384];   // 2 x 32 KiB (h:0-8191, g:8192-)

    const int t = threadIdx.x;
    const int wave = t >> 6, lane = t & 63;
    const int wrt = wave & 1;          // row half (64 rows = 2 mtiles)
    const int wn  = wave >> 1;         // col quarter (32 cols = 1 ntile)
    const int bid = blockIdx.x;
    const int bx  = bid >> 3;          // row tile 0..31
    const int by  = bid & 7;           // col group 0..7
    const int arow0 = bx * 128;
    const int ntb = by * 4;

    // staging geometry: 2 chunks/thread/matrix; id = i*512+t ->
    // rt = id>>8 (0..3), kkg = (id>>6)&3, lc = id&63. Linear both sides.
    const int lc8 = (t & 63) * 8;
    const int rt0s = t >> 8, kkgs = (t >> 6) & 3;
    const size_t sgo0 = ((size_t)(bx * 4 + rt0s) * 64 + kkgs) * 512 + lc8;
    const size_t sgo1 = ((size_t)(bx * 4 + 2 + rt0s) * 64 + kkgs) * 512 + lc8;
    const int sdo0 = (rt0s * 4 + kkgs) * 512 + lc8;
    const int sdo1 = ((2 + rt0s) * 4 + kkgs) * 512 + lc8;

    f16v acc1[2], acc2[2];
    #pragma unroll
    for (int mt = 0; mt < 2; ++mt)
        #pragma unroll
        for (int r = 0; r < 16; ++r) { acc1[mt][r] = 0.f; acc2[mt][r] = 0.f; }

    s8v raH[2], raG[2], rbH[2], rbG[2];
    s8v bA[8], bB[8];

    // prologue: phase 0 -> buf0 directly; phase 1 -> regs; B(0) -> bA
    raH[0] = *(const s8v*)(h1f + sgo0); raH[1] = *(const s8v*)(h1f + sgo1);
    raG[0] = *(const s8v*)(g1f + sgo0); raG[1] = *(const s8v*)(g1f + sgo1);
    {
        u16* wb = &lds[0][0];
        *(s8v*)&wb[sdo0] = raH[0];        *(s8v*)&wb[sdo1] = raH[1];
        *(s8v*)&wb[8192 + sdo0] = raG[0]; *(s8v*)&wb[8192 + sdo1] = raG[1];
    }
    raH[0] = *(const s8v*)(h1f + sgo0 + 2048); raH[1] = *(const s8v*)(h1f + sgo1 + 2048);
    raG[0] = *(const s8v*)(g1f + sgo0 + 2048); raG[1] = *(const s8v*)(g1f + sgo1 + 2048);
    LOADB(bA, 0);
    asm volatile("s_waitcnt lgkmcnt(0)" ::: "memory");
    __builtin_amdgcn_s_barrier();

    for (int p2 = 0; p2 < 8; ++p2) {
        const int p = p2 * 2;
        PHASE(p,     raH, raG, rbH, rbG, bA, bB);
        PHASE(p + 1, rbH, rbG, raH, raG, bB, bA);
    }

    // epilogue: h2 (frag layout) + trace reduction  (R12 verbatim)
    const int l31 = lane & 31, lh = lane >> 5;
    #pragma unroll
    for (int mt = 0; mt < 2; ++mt) {
        const int rt = (arow0 >> 5) + wrt * 2 + mt;
        const int q0 = (ntb + wn) * 32;
        const float bv = b2[q0 + l31];
        const size_t hb = (((size_t)rt * 64 + ((q0 + l31) >> 4)) * 64
                           + (((l31 >> 3) & 1) << 5)) * 8 + (l31 & 7) + lh * 32;
        float tr[16];
        #pragma unroll
        for (int r = 0; r < 16; ++r) {
            float hh = tanh_fast(acc1[mt][r] + bv);
            float gg = 1.f - hh * hh;
            h2f[hb + ((r & 3) + ((r >> 2) << 3)) * 8] = f2bf(hh);
            tr[r] = acc2[mt][r] * gg;
        }
        #pragma unroll
        for (int off = 1; off < 32; off <<= 1)
            #pragma unroll
            for (int r = 0; r < 16; ++r) tr[r] += __shfl_xor(tr[r], off);
        if (l31 == 0) {
            const int rowb = arow0 + (wrt * 2 + mt) * 32 + lh * 4;
            #pragma unroll
            for (int r = 0; r < 16; ++r)
                atomicAdd(&trJ[rowb + (r & 3) + ((r >> 2) << 3)], tr[r]);
        }
    }
}

// ---------------------------------------------------------------------------
// out: y = h2 @ W3 + b3, grid (128, 2).  (R10 verbatim)
// ---------------------------------------------------------------------------
__launch_bounds__(256)
__global__ void cnf_out(const u16* __restrict__ h2f, const u16* __restrict__ W3Tf,
                        const float* __restrict__ b3, const float* __restrict__ trJ,
                        float* __restrict__ out)
{
    __shared__ float red[4][32][32];
    const int t = threadIdx.x;
    const int wave = t >> 6, lane = t & 63;
    const int rt = blockIdx.x;
    const int nb = blockIdx.y;          // column half (32 cols)

    f16v acc;
    #pragma unroll
    for (int r = 0; r < 16; ++r) acc[r] = 0.f;

    #pragma unroll
    for (int kki = 0; kki < 16; ++kki) {
        const int kk = wave * 16 + kki;
        s8v af = *(const s8v*)&h2f[(((size_t)rt * 64 + kk) * 64 + lane) * 8];
        s8v bf = *(const s8v*)&W3Tf[(((size_t)nb * 64 + kk) * 64 + lane) * 8];
        acc = __builtin_amdgcn_mfma_f32_32x32x16_bf16(af, bf, acc, 0, 0, 0);
    }
    const int l31 = lane & 31, lh = lane >> 5;
    #pragma unroll
    for (int r = 0; r < 16; ++r)
        red[wave][(r & 3) + ((r >> 2) << 3) + lh * 4][l31] = acc[r];
    __syncthreads();

    #pragma unroll
    for (int i = 0; i < 4; ++i) {
        int o = t + i * 256;
        int row = o >> 5, col = o & 31;
        float s = red[0][row][col] + red[1][row][col] + red[2][row][col]
                + red[3][row][col] + b3[nb * 32 + col];
        out[(size_t)(rt * 32 + row) * 65 + 1 + nb * 32 + col] = s;
    }
    if (nb == 0 && t < 32) out[(size_t)(rt * 32 + t) * 65] = -trJ[rt * 32 + t];
}

// ---------------------------------------------------------------------------
extern "C" void kernel_launch(void* const* d_in, const int* in_sizes, int n_in,
                              void* d_out, int out_size, void* d_ws, size_t ws_size,
                              hipStream_t stream) {
    const float* x  = (const float*)d_in[0];
    const float* W1 = (const float*)d_in[1];
    const float* b1 = (const float*)d_in[2];
    const float* W2 = (const float*)d_in[3];
    const float* b2 = (const float*)d_in[4];
    const float* W3 = (const float*)d_in[5];
    const float* b3 = (const float*)d_in[6];
    float* out = (float*)d_out;

    char* ws = (char*)d_ws;
    u16*   h1f = (u16*)(ws);                                  //  8 MB (frag layout)
    u16*   g1f = (u16*)(ws + (size_t)( 8u << 20));            //  8 MB (frag layout)
    u16*   h2f = (u16*)(ws + (size_t)(16u << 20));            //  8 MB (frag layout)
    u16*   W2T = (u16*)(ws + (size_t)(24u << 20));            //  2 MB (frag layout)
    u16*   VTb = (u16*)(ws + (size_t)(26u << 20));            //  2 MB (frag layout)
    float* trJ = (float*)(ws + (size_t)(28u << 20));          // 16 KB
    u16*   xbb = (u16*)(ws + (size_t)(28u << 20) + 65536);    // 512 KB
    u16*   W1T = (u16*)(ws + (size_t)(28u << 20) + 65536 + 524288);             // 128 KB
    u16*   W3T = (u16*)(ws + (size_t)(28u << 20) + 65536 + 524288 + 131072);    // 128 KB (frag)

    cnf_prep <<<dim3(32, 32), 256, 0, stream>>>(x, W1, W2, W3, W2T, VTb, xbb, W1T, W3T, trJ);
    cnf_gemm1<<<dim3(32, 16), 256, 0, stream>>>(xbb, W1T, b1, h1f, g1f);
    cnf_mid  <<<256,          512, 0, stream>>>(h1f, g1f, W2T, VTb, b2, h2f, trJ);
    cnf_out  <<<dim3(128, 2), 256, 0, stream>>>(h2f, W3T, b3, trJ, out);
}

// Round 14
// 56.186 us; speedup vs baseline: 1.2308x; 1.0329x over previous
//
#include <hip/hip_runtime.h>
#include <cmath>

typedef unsigned short u16;
typedef __attribute__((ext_vector_type(8))) short s8v;    // 8 bf16 (4 VGPRs)
typedef __attribute__((ext_vector_type(4))) float f4v;    // 16x16 acc / float4
typedef __attribute__((ext_vector_type(16))) float f16v;  // 32x32 acc

__device__ __forceinline__ u16 f2bf(float f) {
    union { float f; unsigned u; } v; v.f = f;
    unsigned r = v.u + 0x7FFFu + ((v.u >> 16) & 1u);   // RNE
    return (u16)(r >> 16);
}
// fast tanh: 1 - 2/(1+exp2(2x*log2e)); |err| ~1e-6
__device__ __forceinline__ float tanh_fast(float x) {
    float e = __builtin_amdgcn_exp2f(x * 2.88539008177792681f);
    return 1.f - 2.f * __builtin_amdgcn_rcpf(1.f + e);
}
// 16x16 subtile swizzled slot (gemm1 input staging; verified R5)
__device__ __forceinline__ int wslot(int row, int c) {
    return ((((c >> 2) << 6) | ((c & 3) << 4) | (row & 15)) ^ c);
}
// fragment-layout flat u16 index for element (n,k), 32x32 frags:
// lane = (n&31) + ((k>>3)&1)*32; j = k&7; tile (n>>5, k>>4)
__device__ __forceinline__ size_t fragoff(int n, int k) {
    return (((size_t)(n >> 5) * 64 + (k >> 4)) * 64 + (n & 31) + (((k >> 3) & 1) << 5)) * 8 + (k & 7);
}

// ---------------------------------------------------------------------------
// prep (grid 32x32, 256 thr):  (R9 verbatim)
// ---------------------------------------------------------------------------
__launch_bounds__(256)
__global__ void cnf_prep(const float* __restrict__ x, const float* __restrict__ W1,
                         const float* __restrict__ W2, const float* __restrict__ W3,
                         u16* __restrict__ W2Tf, u16* __restrict__ VTf,
                         u16* __restrict__ xb, u16* __restrict__ W1T,
                         u16* __restrict__ W3Tf, float* __restrict__ trJ)
{
    __shared__ float w2s[32][33];
    __shared__ __align__(16) float w1s[64][36];   // [i][p], 16B-aligned rows
    const int a = blockIdx.x * 32;   // p / k (rows of W2)
    const int b = blockIdx.y * 32;   // q / n (cols of W2)
    const int t = threadIdx.x;

    #pragma unroll
    for (int it = 0; it < 4; ++it) {
        int idx = t + it * 256;
        w2s[idx >> 5][idx & 31] = W2[(a + (idx >> 5)) * 1024 + b + (idx & 31)];
    }
    #pragma unroll
    for (int it = 0; it < 8; ++it) {
        int idx = t + it * 256;
        w1s[idx >> 5][idx & 31] = W1[(idx >> 5) * 1024 + a + (idx & 31)];
    }
    __syncthreads();

    #pragma unroll
    for (int it = 0; it < 4; ++it) {
        int idx = t + it * 256;
        int rr = idx >> 5, cc = idx & 31;
        W2Tf[fragoff(b + rr, a + cc)] = f2bf(w2s[cc][rr]);
    }
    {
        const int q = t >> 3, pg = t & 7;
        const float* w3row = W3 + (b + q) * 64;
        f4v u = f4v{0.f, 0.f, 0.f, 0.f};
        #pragma unroll
        for (int i4 = 0; i4 < 16; ++i4) {
            f4v w3v = *(const f4v*)&w3row[i4 * 4];
            #pragma unroll
            for (int s = 0; s < 4; ++s) {
                f4v wv = *(const f4v*)&w1s[i4 * 4 + s][pg * 4];
                u += w3v[s] * wv;
            }
        }
        #pragma unroll
        for (int j = 0; j < 4; ++j) {
            const int pp = pg * 4 + j;
            VTf[fragoff(b + q, a + pp)] = f2bf(w2s[pp][q] * u[j]);
        }
    }
    {
        int bid = blockIdx.y * 32 + blockIdx.x;
        int e = bid * 256 + t;
        xb[e] = f2bf(x[(e >> 6) * 65 + 1 + (e & 63)]);
    }
    if (blockIdx.y == 0) {
        int pp = t >> 3, i0 = (t & 7) * 8;
        s8v v;
        #pragma unroll
        for (int j = 0; j < 8; ++j) v[j] = (short)f2bf(w1s[i0 + j][pp]);
        *(s8v*)&W1T[(a + pp) * 64 + i0] = v;
        if (t < 128) trJ[blockIdx.x * 128 + t] = 0.f;
    }
    if (blockIdx.y == 1) {
        int idx = blockIdx.x * 256 + t;
        int n = idx & 63, k0 = (idx >> 6) * 8;
        s8v v;
        #pragma unroll
        for (int j = 0; j < 8; ++j) v[j] = (short)f2bf(W3[(k0 + j) * 64 + n]);
        *(s8v*)&W3Tf[fragoff(n, k0)] = v;
    }
}

// ---------------------------------------------------------------------------
// gemm1 (MFMA 16x16x32): h1 = tanh(xb @ W1T^T + b1), g1 = 1-h1^2
// OUTPUT IN 32x32 A-FRAGMENT LAYOUT (h1f/g1f).  (R12 verbatim, verified)
// ---------------------------------------------------------------------------
__launch_bounds__(256)
__global__ void cnf_gemm1(const u16* __restrict__ xb, const u16* __restrict__ W1T,
                          const float* __restrict__ b1,
                          u16* __restrict__ h1f, u16* __restrict__ g1f)
{
    __shared__ __align__(16) u16 lds[12 * 1024];   // 24 KB input staging
    __shared__ __align__(16) u16 hls[128 * 64];    // 16 KB
    __shared__ __align__(16) u16 gls[128 * 64];    // 16 KB
    const int t = threadIdx.x;
    const int wave = t >> 6, lane = t & 63;
    const int wm = wave >> 1, wn = wave & 1;
    const int g = lane >> 4, lr = lane & 15;
    const int arow0 = blockIdx.x * 128, bcol0 = blockIdx.y * 64;

    #pragma unroll
    for (int i = 0; i < 4; ++i) {
        int ch = t + i * 256, row = ch >> 3, c = ch & 7;
        *(s8v*)&lds[(row >> 4) * 1024 + wslot(row, c) * 8] =
            *(const s8v*)&xb[(arow0 + row) * 64 + c * 8];
    }
    #pragma unroll
    for (int i = 0; i < 2; ++i) {
        int ch = t + i * 256, row = ch >> 3, c = ch & 7;
        *(s8v*)&lds[(8 + (row >> 4)) * 1024 + wslot(row, c) * 8] =
            *(const s8v*)&W1T[(bcol0 + row) * 64 + c * 8];
    }
    __syncthreads();

    f4v acc[4][2];
    #pragma unroll
    for (int mi = 0; mi < 4; ++mi)
        #pragma unroll
        for (int ni = 0; ni < 2; ++ni) acc[mi][ni] = f4v{0.f,0.f,0.f,0.f};

    #pragma unroll
    for (int ks = 0; ks < 2; ++ks) {
        const int lo = (ks * 64 + (lane ^ ((ks * 4 + g) & 7))) * 8;
        s8v af[4], bf[2];
        #pragma unroll
        for (int mi = 0; mi < 4; ++mi) af[mi] = *(const s8v*)&lds[(wm * 4 + mi) * 1024 + lo];
        #pragma unroll
        for (int ni = 0; ni < 2; ++ni) bf[ni] = *(const s8v*)&lds[(8 + wn * 2 + ni) * 1024 + lo];
        #pragma unroll
        for (int mi = 0; mi < 4; ++mi)
            #pragma unroll
            for (int ni = 0; ni < 2; ++ni)
                acc[mi][ni] = __builtin_amdgcn_mfma_f32_16x16x32_bf16(af[mi], bf[ni], acc[mi][ni], 0, 0, 0);
    }

    #pragma unroll
    for (int mi = 0; mi < 4; ++mi) {
        const int rowl = wm * 64 + mi * 16 + g * 4;
        #pragma unroll
        for (int ni = 0; ni < 2; ++ni) {
            const int coll = wn * 32 + ni * 16 + lr;
            const float bv = b1[bcol0 + coll];
            const int cc = coll >> 3, jj = coll & 7;
            #pragma unroll
            for (int r = 0; r < 4; ++r) {
                const int row = rowl + r;
                float h = tanh_fast(acc[mi][ni][r] + bv);
                int idx = row * 64 + ((cc ^ (row & 7)) << 3) + jj;
                hls[idx] = f2bf(h);
                gls[idx] = f2bf(1.f - h * h);
            }
        }
    }
    __syncthreads();

    const int rt0 = arow0 >> 5, kk0 = bcol0 >> 4;
    #pragma unroll
    for (int i = 0; i < 4; ++i) {
        const int tile = (i * 256 + t) >> 6;       // 0..15
        const int ln = t & 63;
        const int rt = tile >> 2, kk = tile & 3;
        const int row = rt * 32 + (ln & 31);
        const int kb = kk * 16 + (ln >> 5) * 8;
        const int src = row * 64 + (((kb >> 3) ^ (row & 7)) << 3);
        const size_t dst = ((size_t)(rt0 + rt) * 64 + (kk0 + kk)) * 512 + ln * 8;
        *(s8v*)&h1f[dst] = *(const s8v*)&hls[src];
        *(s8v*)&g1f[dst] = *(const s8v*)&gls[src];
    }
}

// ---------------------------------------------------------------------------
// mid: fused dual GEMM, K=1024. TILE 128x64, 256 thr (4 waves), grid (32,16)
// = 512 blocks = 2-3 blocks/CU -> cross-BLOCK overlap hides barrier drains
// (the m97 mechanism; 1-block/CU variants R9-R13 all stalled there).
// Wave tile 64x32 (wrt=wave&1 row-half, wn=wave>>1 col-half), 8 MFMA/kt/wave.
// A (h1f/g1f frag layout) reg-staged 2 kt ahead -> linear LDS ping-pong
// (2 x 16KB); B (W2Tf/VTf) reg-prefetched 1 kt ahead. One barrier per kt.
//   C2 = h1@W2 -> h2f (frag layout); T = g1@V -> trJ += rowsum(T*g2)
// ---------------------------------------------------------------------------
#define LOADB(B, kt)                                                           \
    do { _Pragma("unroll")                                                     \
         for (int _ks = 0; _ks < 2; ++_ks) {                                   \
             size_t _o = (((size_t)(ntb + wn) * 64 + (kt) * 2 + _ks) * 512) + lane * 8; \
             B[_ks*2 + 0] = *(const s8v*)&W2Tf[_o];                            \
             B[_ks*2 + 1] = *(const s8v*)&VTf[_o];                             \
         } } while (0)

#define MIDBODY(kt, AwH, AwG, AlH, AlG, Bc, Bn)                                \
    {                                                                          \
        const u16* _buf = &lds[(kt) & 1][0];                                   \
        s8v a1[2][2], a2[2][2];  /* [ks][mt] */                                \
        _Pragma("unroll")                                                      \
        for (int ks = 0; ks < 2; ++ks)                                         \
            _Pragma("unroll")                                                  \
            for (int mt = 0; mt < 2; ++mt) {                                   \
                const int f = ((wrt * 2 + mt) * 2 + ks) * 512 + lane * 8;      \
                a1[ks][mt] = *(const s8v*)&_buf[f];                            \
                a2[ks][mt] = *(const s8v*)&_buf[4096 + f];                     \
            }                                                                  \
        if ((kt) < 30) {                                                       \
            const size_t _go = (size_t)((kt) + 2) * 1024;                      \
            AlH[0] = *(const s8v*)(h1f + sg0 + _go);                           \
            AlH[1] = *(const s8v*)(h1f + sg1 + _go);                           \
            AlG[0] = *(const s8v*)(g1f + sg0 + _go);                           \
            AlG[1] = *(const s8v*)(g1f + sg1 + _go);                           \
        }                                                                      \
        if ((kt) < 31) {                                                       \
            u16* _wb = &lds[((kt) + 1) & 1][0];                                \
            *(s8v*)&_wb[sd0] = AwH[0];        *(s8v*)&_wb[sd1] = AwH[1];       \
            *(s8v*)&_wb[4096 + sd0] = AwG[0]; *(s8v*)&_wb[4096 + sd1] = AwG[1];\
            LOADB(Bn, (kt) + 1);                                               \
        }                                                                      \
        _Pragma("unroll")                                                      \
        for (int ks = 0; ks < 2; ++ks)                                         \
            _Pragma("unroll")                                                  \
            for (int mt = 0; mt < 2; ++mt) {                                   \
                acc1[mt] = __builtin_amdgcn_mfma_f32_32x32x16_bf16(a1[ks][mt], Bc[ks*2+0], acc1[mt], 0, 0, 0); \
                acc2[mt] = __builtin_amdgcn_mfma_f32_32x32x16_bf16(a2[ks][mt], Bc[ks*2+1], acc2[mt], 0, 0, 0); \
            }                                                                  \
        __syncthreads();                                                       \
    }

__launch_bounds__(256)
__global__ void cnf_mid(const u16* __restrict__ h1f, const u16* __restrict__ g1f,
                        const u16* __restrict__ W2Tf, const u16* __restrict__ VTf,
                        const float* __restrict__ b2,
                        u16* __restrict__ h2f, float* __restrict__ trJ)
{
    __shared__ __align__(16) u16 lds[2][8192];   // 2 x 16 KiB (h:0-4095, g:4096-)

    const int t = threadIdx.x;
    const int wave = t >> 6, lane = t & 63;
    const int wrt = wave & 1;          // row half (64 rows = 2 mtiles)
    const int wn  = wave >> 1;         // col half (32 cols = 1 ntile)
    const int bx = blockIdx.x;         // row tile 0..31
    const int by = blockIdx.y;         // col group 0..15 (2 ntiles)
    const int arow0 = bx * 128;
    const int ntb = by * 2;

    // A staging: 2 chunks/thread/matrix; c = i*256+t -> rt=c>>7, kk=(c>>6)&1,
    // lc=c&63. Linear global (frag stream) and linear LDS.
    const int lc8 = (t & 63) * 8;
    const int c0rt = t >> 7, c0kk = (t >> 6) & 1;
    const size_t sg0 = ((size_t)(bx * 4 + c0rt) * 64 + c0kk) * 512 + lc8;
    const size_t sg1 = ((size_t)(bx * 4 + 2 + c0rt) * 64 + c0kk) * 512 + lc8;
    const int sd0 = (c0rt * 2 + c0kk) * 512 + lc8;
    const int sd1 = ((2 + c0rt) * 2 + c0kk) * 512 + lc8;

    f16v acc1[2], acc2[2];
    #pragma unroll
    for (int mt = 0; mt < 2; ++mt)
        #pragma unroll
        for (int r = 0; r < 16; ++r) { acc1[mt][r] = 0.f; acc2[mt][r] = 0.f; }

    s8v raH[2], raG[2], rbH[2], rbG[2];
    s8v bA[4], bB[4];

    // prologue: kt=0 -> buf0; kt=1 -> regs; B(0) -> bA
    raH[0] = *(const s8v*)(h1f + sg0); raH[1] = *(const s8v*)(h1f + sg1);
    raG[0] = *(const s8v*)(g1f + sg0); raG[1] = *(const s8v*)(g1f + sg1);
    {
        u16* wb = &lds[0][0];
        *(s8v*)&wb[sd0] = raH[0];        *(s8v*)&wb[sd1] = raH[1];
        *(s8v*)&wb[4096 + sd0] = raG[0]; *(s8v*)&wb[4096 + sd1] = raG[1];
    }
    raH[0] = *(const s8v*)(h1f + sg0 + 1024); raH[1] = *(const s8v*)(h1f + sg1 + 1024);
    raG[0] = *(const s8v*)(g1f + sg0 + 1024); raG[1] = *(const s8v*)(g1f + sg1 + 1024);
    LOADB(bA, 0);
    __syncthreads();

    for (int kt2 = 0; kt2 < 16; ++kt2) {
        const int kt = kt2 * 2;
        MIDBODY(kt,     raH, raG, rbH, rbG, bA, bB);
        MIDBODY(kt + 1, rbH, rbG, raH, raG, bB, bA);
    }

    // epilogue: h2 (frag layout) + trace reduction (verified R12 formulas)
    const int l31 = lane & 31, lh = lane >> 5;
    #pragma unroll
    for (int mt = 0; mt < 2; ++mt) {
        const int rt = (arow0 >> 5) + wrt * 2 + mt;
        const int q0 = (ntb + wn) * 32;
        const float bv = b2[q0 + l31];
        const size_t hb = (((size_t)rt * 64 + ((q0 + l31) >> 4)) * 64
                           + (((l31 >> 3) & 1) << 5)) * 8 + (l31 & 7) + lh * 32;
        float tr[16];
        #pragma unroll
        for (int r = 0; r < 16; ++r) {
            float hh = tanh_fast(acc1[mt][r] + bv);
            float gg = 1.f - hh * hh;
            h2f[hb + ((r & 3) + ((r >> 2) << 3)) * 8] = f2bf(hh);
            tr[r] = acc2[mt][r] * gg;
        }
        #pragma unroll
        for (int off = 1; off < 32; off <<= 1)
            #pragma unroll
            for (int r = 0; r < 16; ++r) tr[r] += __shfl_xor(tr[r], off);
        if (l31 == 0) {
            const int rowb = arow0 + (wrt * 2 + mt) * 32 + lh * 4;
            #pragma unroll
            for (int r = 0; r < 16; ++r)
                atomicAdd(&trJ[rowb + (r & 3) + ((r >> 2) << 3)], tr[r]);
        }
    }
}

// ---------------------------------------------------------------------------
// out: y = h2 @ W3 + b3, grid (128, 2).  (R10 verbatim)
// ---------------------------------------------------------------------------
__launch_bounds__(256)
__global__ void cnf_out(const u16* __restrict__ h2f, const u16* __restrict__ W3Tf,
                        const float* __restrict__ b3, const float* __restrict__ trJ,
                        float* __restrict__ out)
{
    __shared__ float red[4][32][32];
    const int t = threadIdx.x;
    const int wave = t >> 6, lane = t & 63;
    const int rt = blockIdx.x;
    const int nb = blockIdx.y;          // column half (32 cols)

    f16v acc;
    #pragma unroll
    for (int r = 0; r < 16; ++r) acc[r] = 0.f;

    #pragma unroll
    for (int kki = 0; kki < 16; ++kki) {
        const int kk = wave * 16 + kki;
        s8v af = *(const s8v*)&h2f[(((size_t)rt * 64 + kk) * 64 + lane) * 8];
        s8v bf = *(const s8v*)&W3Tf[(((size_t)nb * 64 + kk) * 64 + lane) * 8];
        acc = __builtin_amdgcn_mfma_f32_32x32x16_bf16(af, bf, acc, 0, 0, 0);
    }
    const int l31 = lane & 31, lh = lane >> 5;
    #pragma unroll
    for (int r = 0; r < 16; ++r)
        red[wave][(r & 3) + ((r >> 2) << 3) + lh * 4][l31] = acc[r];
    __syncthreads();

    #pragma unroll
    for (int i = 0; i < 4; ++i) {
        int o = t + i * 256;
        int row = o >> 5, col = o & 31;
        float s = red[0][row][col] + red[1][row][col] + red[2][row][col]
                + red[3][row][col] + b3[nb * 32 + col];
        out[(size_t)(rt * 32 + row) * 65 + 1 + nb * 32 + col] = s;
    }
    if (nb == 0 && t < 32) out[(size_t)(rt * 32 + t) * 65] = -trJ[rt * 32 + t];
}

// ---------------------------------------------------------------------------
extern "C" void kernel_launch(void* const* d_in, const int* in_sizes, int n_in,
                              void* d_out, int out_size, void* d_ws, size_t ws_size,
                              hipStream_t stream) {
    const float* x  = (const float*)d_in[0];
    const float* W1 = (const float*)d_in[1];
    const float* b1 = (const float*)d_in[2];
    const float* W2 = (const float*)d_in[3];
    const float* b2 = (const float*)d_in[4];
    const float* W3 = (const float*)d_in[5];
    const float* b3 = (const float*)d_in[6];
    float* out = (float*)d_out;

    char* ws = (char*)d_ws;
    u16*   h1f = (u16*)(ws);                                  //  8 MB (frag layout)
    u16*   g1f = (u16*)(ws + (size_t)( 8u << 20));            //  8 MB (frag layout)
    u16*   h2f = (u16*)(ws + (size_t)(16u << 20));            //  8 MB (frag layout)
    u16*   W2T = (u16*)(ws + (size_t)(24u << 20));            //  2 MB (frag layout)
    u16*   VTb = (u16*)(ws + (size_t)(26u << 20));            //  2 MB (frag layout)
    float* trJ = (float*)(ws + (size_t)(28u << 20));          // 16 KB
    u16*   xbb = (u16*)(ws + (size_t)(28u << 20) + 65536);    // 512 KB
    u16*   W1T = (u16*)(ws + (size_t)(28u << 20) + 65536 + 524288);             // 128 KB
    u16*   W3T = (u16*)(ws + (size_t)(28u << 20) + 65536 + 524288 + 131072);    // 128 KB (frag)

    cnf_prep <<<dim3(32, 32), 256, 0, stream>>>(x, W1, W2, W3, W2T, VTb, xbb, W1T, W3T, trJ);
    cnf_gemm1<<<dim3(32, 16), 256, 0, stream>>>(xbb, W1T, b1, h1f, g1f);
    cnf_mid  <<<dim3(32, 16), 256, 0, stream>>>(h1f, g1f, W2T, VTb, b2, h2f, trJ);
    cnf_out  <<<dim3(128, 2), 256, 0, stream>>>(h2f, W3T, b3, trJ, out);
}